// Round 1
// baseline (4838.240 us; speedup 1.0000x reference)
//
#include <hip/hip_runtime.h>

#define NEG_SLOPE 0.2f
static constexpr int BLK = 256;

// order-preserving float -> uint transform for atomicMax on floats
__device__ __forceinline__ unsigned fkey(float f){
    unsigned b = __float_as_uint(f);
    return (b & 0x80000000u) ? ~b : (b | 0x80000000u);
}
__device__ __forceinline__ float finv(unsigned u){
    unsigned b = (u & 0x80000000u) ? (u ^ 0x80000000u) : ~u;
    return __uint_as_float(b);
}

// buf[i] = bias[i & cmask]  (broadcast bias row over all rows)
__global__ __launch_bounds__(BLK) void bcast_init(float* __restrict__ buf,
                                                  const float* __restrict__ bias,
                                                  int cmask, long total){
    long i = (long)blockIdx.x * BLK + threadIdx.x;
    if (i < total) buf[i] = bias[i & cmask];
}

// H = X @ W   (X: [N,128], W: [128,CO]); also as_out[n] = H[n,:]·avs, ad_out[n] = H[n,:]·avd
// Each thread computes a 4-row x 4-col register tile. CO/4 consecutive threads share 4 rows.
template<int CO, bool RELU_IN>
__global__ __launch_bounds__(BLK) void gemm_att(
    const float* __restrict__ X, const float* __restrict__ W,
    const float* __restrict__ avs, const float* __restrict__ avd,
    float* __restrict__ H, float* __restrict__ as_out, float* __restrict__ ad_out,
    int N)
{
    constexpr int TPR = CO / 4;   // threads per 4-row group (32 or 16)
    long gid = (long)blockIdx.x * BLK + threadIdx.x;
    int group = (int)(gid / TPR);
    int sub   = (int)(gid % TPR);
    int r0 = group * 4;
    if (r0 >= N) return;
    int c0 = sub * 4;

    const float* xr[4];
    #pragma unroll
    for (int i = 0; i < 4; i++) xr[i] = X + (long)min(r0 + i, N - 1) * 128;

    float4 acc[4];
    #pragma unroll
    for (int i = 0; i < 4; i++) acc[i] = make_float4(0.f, 0.f, 0.f, 0.f);

    #pragma unroll 4
    for (int k = 0; k < 128; k++){
        float4 w = *(const float4*)(W + k * CO + c0);
        #pragma unroll
        for (int i = 0; i < 4; i++){
            float xv = xr[i][k];
            if (RELU_IN) xv = fmaxf(xv, 0.f);
            acc[i].x += xv * w.x;
            acc[i].y += xv * w.y;
            acc[i].z += xv * w.z;
            acc[i].w += xv * w.w;
        }
    }

    float4 vs4 = *(const float4*)(avs + c0);
    float4 vd4 = *(const float4*)(avd + c0);
    float ssum[4], dsum[4];
    #pragma unroll
    for (int i = 0; i < 4; i++){
        ssum[i] = acc[i].x*vs4.x + acc[i].y*vs4.y + acc[i].z*vs4.z + acc[i].w*vs4.w;
        dsum[i] = acc[i].x*vd4.x + acc[i].y*vd4.y + acc[i].z*vd4.z + acc[i].w*vd4.w;
        if (r0 + i < N) *(float4*)(H + (long)(r0 + i) * CO + c0) = acc[i];
    }
    // reduce across the TPR lanes of this row-group (TPR divides 64, groups lane-aligned)
    #pragma unroll
    for (int off = TPR >> 1; off > 0; off >>= 1){
        #pragma unroll
        for (int i = 0; i < 4; i++){
            ssum[i] += __shfl_xor(ssum[i], off, 64);
            dsum[i] += __shfl_xor(dsum[i], off, 64);
        }
    }
    if (sub == 0){
        #pragma unroll
        for (int i = 0; i < 4; i++){
            if (r0 + i < N){ as_out[r0 + i] = ssum[i]; ad_out[r0 + i] = dsum[i]; }
        }
    }
}

// pass 1 over edges: e = leaky_relu(as[src] + ad[dst]); store; atomic segment-max by dst
__global__ __launch_bounds__(BLK) void edge_max(
    const int* __restrict__ src, const int* __restrict__ dst, int E, int Etot,
    const float* __restrict__ as, const float* __restrict__ ad,
    float* __restrict__ ebuf, unsigned* __restrict__ mu)
{
    int e = blockIdx.x * BLK + threadIdx.x;
    if (e >= Etot) return;
    int s, d;
    if (e < E){ s = src[e]; d = dst[e]; } else { s = e - E; d = s; }
    float v = as[s] + ad[d];
    v = v > 0.f ? v : NEG_SLOPE * v;
    ebuf[e] = v;
    atomicMax(mu + d, fkey(v));
}

// pass 2: ex = exp(e - m[dst]); store; atomic segment-sum of denominators
__global__ __launch_bounds__(BLK) void edge_exp(
    const int* __restrict__ dst, int E, int Etot,
    const unsigned* __restrict__ mu,
    float* __restrict__ ebuf, float* __restrict__ den)
{
    int e = blockIdx.x * BLK + threadIdx.x;
    if (e >= Etot) return;
    int d = (e < E) ? dst[e] : (e - E);
    float m = finv(mu[d]);
    float ex = __expf(ebuf[e] - m);
    ebuf[e] = ex;
    unsafeAtomicAdd(den + d, ex);
}

// pass 3: out[dst,:] += h[src,:] * alpha ; CO/4 threads per edge, float4 reads, 4 atomics each
template<int CO>
__global__ __launch_bounds__(BLK) void edge_agg(
    const int* __restrict__ src, const int* __restrict__ dst, int E, int Etot,
    const float* __restrict__ h, const float* __restrict__ ebuf,
    const float* __restrict__ den, float* __restrict__ out)
{
    constexpr int TPE = CO / 4;
    long gid = (long)blockIdx.x * BLK + threadIdx.x;
    int e   = (int)(gid / TPE);
    int sub = (int)(gid % TPE);
    if (e >= Etot) return;
    int s, d;
    if (e < E){ s = src[e]; d = dst[e]; } else { s = e - E; d = s; }
    float alpha = ebuf[e] / (den[d] + 1e-16f);
    float4 hv = *(const float4*)(h + (long)s * CO + sub * 4);
    float* o = out + (long)d * CO + sub * 4;
    unsafeAtomicAdd(o + 0, hv.x * alpha);
    unsafeAtomicAdd(o + 1, hv.y * alpha);
    unsafeAtomicAdd(o + 2, hv.z * alpha);
    unsafeAtomicAdd(o + 3, hv.w * alpha);
}

static inline int cdiv(long a, long b){ return (int)((a + b - 1) / b); }

extern "C" void kernel_launch(void* const* d_in, const int* in_sizes, int n_in,
                              void* d_out, int out_size, void* d_ws, size_t ws_size,
                              hipStream_t stream)
{
    const float* fea  = (const float*)d_in[0];  // [B,N,128]
    const int*   ei   = (const int*)  d_in[1];  // [B,2,E]
    const float* W1   = (const float*)d_in[2];  // [128,128]
    const float* av_s1= (const float*)d_in[3];  // [1,128]
    const float* av_d1= (const float*)d_in[4];
    const float* b1   = (const float*)d_in[5];  // [128]
    const float* W2   = (const float*)d_in[6];  // [128,64]
    const float* av_s2= (const float*)d_in[7];  // [1,64]
    const float* av_d2= (const float*)d_in[8];
    const float* b2   = (const float*)d_in[9];  // [64]
    float* out = (float*)d_out;

    const int B = 2;
    const int N = out_size / (B * 64);          // 50000
    const int E = in_sizes[1] / (2 * B);        // 800000
    const int Etot = E + N;                     // with self-loops

    // workspace layout (floats)
    float* ws = (float*)d_ws;
    size_t off = 0;
    float* h1   = ws + off; off += (size_t)N * 128;
    float* agg1 = ws + off; off += (size_t)N * 128;
    float* h2   = ws + off; off += (size_t)N * 64;
    float* as1  = ws + off; off += N;
    float* ad1  = ws + off; off += N;
    float* as2  = ws + off; off += N;
    float* ad2  = ws + off; off += N;
    unsigned* m1u = (unsigned*)(ws + off); off += N;
    float*    den1= ws + off; off += N;
    unsigned* m2u = (unsigned*)(ws + off); off += N;
    float*    den2= ws + off; off += N;
    float* ebuf = ws + off; off += Etot;
    // total ~17.25M floats (~69 MB)

    for (int b = 0; b < B; b++){
        const int* srcp = ei + (size_t)b * 2 * E;
        const int* dstp = srcp + E;
        const float* xb = fea + (size_t)b * N * 128;
        float* outb = out + (size_t)b * N * 64;

        // init segment-max keys (0 == below all real keys) and denominators
        hipMemsetAsync(m1u, 0, (size_t)4 * N * sizeof(float), stream);
        // agg1 <- b1 broadcast, out <- b2 broadcast (bias pre-applied before scatter)
        bcast_init<<<cdiv((long)N*128, BLK), BLK, 0, stream>>>(agg1, b1, 127, (long)N*128);
        bcast_init<<<cdiv((long)N*64,  BLK), BLK, 0, stream>>>(outb, b2, 63,  (long)N*64);

        // ---- layer 1 ----
        {
            long th = (long)((N + 3) / 4) * 32;
            gemm_att<128,false><<<cdiv(th, BLK), BLK, 0, stream>>>(xb, W1, av_s1, av_d1, h1, as1, ad1, N);
        }
        edge_max<<<cdiv(Etot, BLK), BLK, 0, stream>>>(srcp, dstp, E, Etot, as1, ad1, ebuf, m1u);
        edge_exp<<<cdiv(Etot, BLK), BLK, 0, stream>>>(dstp, E, Etot, m1u, ebuf, den1);
        edge_agg<128><<<cdiv((long)Etot*32, BLK), BLK, 0, stream>>>(srcp, dstp, E, Etot, h1, ebuf, den1, agg1);

        // ---- layer 2 (input = relu(agg1), agg1 already includes b1) ----
        {
            long th = (long)((N + 3) / 4) * 16;
            gemm_att<64,true><<<cdiv(th, BLK), BLK, 0, stream>>>(agg1, W2, av_s2, av_d2, h2, as2, ad2, N);
        }
        edge_max<<<cdiv(Etot, BLK), BLK, 0, stream>>>(srcp, dstp, E, Etot, as2, ad2, ebuf, m2u);
        edge_exp<<<cdiv(Etot, BLK), BLK, 0, stream>>>(dstp, E, Etot, m2u, ebuf, den2);
        edge_agg<64><<<cdiv((long)Etot*16, BLK), BLK, 0, stream>>>(srcp, dstp, E, Etot, h2, ebuf, den2, outb);
    }
}

// Round 2
// 623.047 us; speedup vs baseline: 7.7654x; 7.7654x over previous
//
#include <hip/hip_runtime.h>

#define NEG_SLOPE 0.2f
static constexpr int BLK = 256;

static inline int cdiv(long a, long b){ return (int)((a + b - 1) / b); }

// ------------------- GEMM + attention dots (unchanged from R1) -------------------
// H = X @ W   (X: [N,128], W: [128,CO]); also as_out[n] = H[n,:]·avs, ad_out[n] = H[n,:]·avd
template<int CO, bool RELU_IN>
__global__ __launch_bounds__(BLK) void gemm_att(
    const float* __restrict__ X, const float* __restrict__ W,
    const float* __restrict__ avs, const float* __restrict__ avd,
    float* __restrict__ H, float* __restrict__ as_out, float* __restrict__ ad_out,
    int N)
{
    constexpr int TPR = CO / 4;   // threads per 4-row group (32 or 16)
    long gid = (long)blockIdx.x * BLK + threadIdx.x;
    int group = (int)(gid / TPR);
    int sub   = (int)(gid % TPR);
    int r0 = group * 4;
    if (r0 >= N) return;
    int c0 = sub * 4;

    const float* xr[4];
    #pragma unroll
    for (int i = 0; i < 4; i++) xr[i] = X + (long)min(r0 + i, N - 1) * 128;

    float4 acc[4];
    #pragma unroll
    for (int i = 0; i < 4; i++) acc[i] = make_float4(0.f, 0.f, 0.f, 0.f);

    #pragma unroll 4
    for (int k = 0; k < 128; k++){
        float4 w = *(const float4*)(W + k * CO + c0);
        #pragma unroll
        for (int i = 0; i < 4; i++){
            float xv = xr[i][k];
            if (RELU_IN) xv = fmaxf(xv, 0.f);
            acc[i].x += xv * w.x;
            acc[i].y += xv * w.y;
            acc[i].z += xv * w.z;
            acc[i].w += xv * w.w;
        }
    }

    float4 vs4 = *(const float4*)(avs + c0);
    float4 vd4 = *(const float4*)(avd + c0);
    float ssum[4], dsum[4];
    #pragma unroll
    for (int i = 0; i < 4; i++){
        ssum[i] = acc[i].x*vs4.x + acc[i].y*vs4.y + acc[i].z*vs4.z + acc[i].w*vs4.w;
        dsum[i] = acc[i].x*vd4.x + acc[i].y*vd4.y + acc[i].z*vd4.z + acc[i].w*vd4.w;
        if (r0 + i < N) *(float4*)(H + (long)(r0 + i) * CO + c0) = acc[i];
    }
    #pragma unroll
    for (int off = TPR >> 1; off > 0; off >>= 1){
        #pragma unroll
        for (int i = 0; i < 4; i++){
            ssum[i] += __shfl_xor(ssum[i], off, 64);
            dsum[i] += __shfl_xor(dsum[i], off, 64);
        }
    }
    if (sub == 0){
        #pragma unroll
        for (int i = 0; i < 4; i++){
            if (r0 + i < N){ as_out[r0 + i] = ssum[i]; ad_out[r0 + i] = dsum[i]; }
        }
    }
}

// ------------------- CSR build (per graph; shared by both layers) -------------------
__global__ __launch_bounds__(BLK) void count_dst(
    const int* __restrict__ dst, int E, int Etot, int* __restrict__ counts)
{
    int e = blockIdx.x * BLK + threadIdx.x;
    if (e >= Etot) return;
    int d = (e < E) ? dst[e] : (e - E);
    atomicAdd(counts + d, 1);
}

__global__ __launch_bounds__(256) void scan1_k(
    const int* __restrict__ counts, int N, int* __restrict__ scan1, int* __restrict__ bsum)
{
    __shared__ int sh[256];
    int i = blockIdx.x * 256 + threadIdx.x;
    int v = (i < N) ? counts[i] : 0;
    sh[threadIdx.x] = v;
    __syncthreads();
    #pragma unroll
    for (int off = 1; off < 256; off <<= 1){
        int t = (threadIdx.x >= off) ? sh[threadIdx.x - off] : 0;
        __syncthreads();
        sh[threadIdx.x] += t;
        __syncthreads();
    }
    if (i < N) scan1[i] = sh[threadIdx.x];
    if (threadIdx.x == 255) bsum[blockIdx.x] = sh[255];
}

__global__ __launch_bounds__(256) void scan2_k(int* __restrict__ bsum, int nb)
{
    __shared__ int sh[256];
    int v = (threadIdx.x < nb) ? bsum[threadIdx.x] : 0;
    sh[threadIdx.x] = v;
    __syncthreads();
    #pragma unroll
    for (int off = 1; off < 256; off <<= 1){
        int t = (threadIdx.x >= off) ? sh[threadIdx.x - off] : 0;
        __syncthreads();
        sh[threadIdx.x] += t;
        __syncthreads();
    }
    if (threadIdx.x < nb) bsum[threadIdx.x] = sh[threadIdx.x] - v;  // exclusive
}

__global__ __launch_bounds__(256) void scan3_k(
    const int* __restrict__ counts, const int* __restrict__ scan1,
    const int* __restrict__ bsum, int N, int Etot, int* __restrict__ rowptr)
{
    int i = blockIdx.x * 256 + threadIdx.x;
    if (i < N) rowptr[i] = scan1[i] - counts[i] + bsum[blockIdx.x];
    if (i == 0) rowptr[N] = Etot;
}

__global__ __launch_bounds__(BLK) void scatter_src(
    const int* __restrict__ src, const int* __restrict__ dst, int E, int Etot,
    const int* __restrict__ rowptr, int* __restrict__ fill, int* __restrict__ csr_src)
{
    int e = blockIdx.x * BLK + threadIdx.x;
    if (e >= Etot) return;
    int s, d;
    if (e < E){ s = src[e]; d = dst[e]; } else { s = e - E; d = s; }
    int pos = rowptr[d] + atomicAdd(fill + d, 1);
    csr_src[pos] = s;
}

// ------------------- fused softmax + aggregation, one wave per dst node -------------------
template<int CO>
__global__ __launch_bounds__(BLK) void node_agg(
    const int* __restrict__ rowptr, const int* __restrict__ csr_src,
    const float* __restrict__ as, const float* __restrict__ ad,
    const float* __restrict__ h, const float* __restrict__ bias,
    float* __restrict__ out, int N)
{
    constexpr int VPL = CO / 64;  // floats per lane (2 for CO=128, 1 for CO=64)
    int node = blockIdx.x * (BLK / 64) + (threadIdx.x >> 6);
    int lane = threadIdx.x & 63;
    if (node >= N) return;
    int start = rowptr[node];
    int deg   = rowptr[node + 1] - start;
    float adv = ad[node];
    float acc[VPL];
    #pragma unroll
    for (int i = 0; i < VPL; i++) acc[i] = 0.f;

    if (deg <= 64){
        int   s = 0;
        float e = -1e30f;
        if (lane < deg){
            s = csr_src[start + lane];
            float v = as[s] + adv;
            e = v > 0.f ? v : NEG_SLOPE * v;
        }
        float m = e;
        #pragma unroll
        for (int off = 32; off; off >>= 1) m = fmaxf(m, __shfl_xor(m, off, 64));
        float ex = (lane < deg) ? __expf(e - m) : 0.f;
        float sum = ex;
        #pragma unroll
        for (int off = 32; off; off >>= 1) sum += __shfl_xor(sum, off, 64);
        float alpha = ex / (sum + 1e-16f);

        for (int j = 0; j < deg; j++){
            int   sj = __shfl(s, j, 64);
            float aj = __shfl(alpha, j, 64);
            const float* hr = h + (long)sj * CO + lane * VPL;
            if (VPL == 2){
                float2 hv = *(const float2*)hr;
                acc[0] += aj * hv.x;
                acc[VPL - 1] += aj * hv.y;
            } else {
                acc[0] += aj * hr[0];
            }
        }
    } else {
        // rare fallback for deg > 64
        float m = -1e30f;
        for (int j = lane; j < deg; j += 64){
            int sj = csr_src[start + j];
            float v = as[sj] + adv; v = v > 0.f ? v : NEG_SLOPE * v;
            m = fmaxf(m, v);
        }
        #pragma unroll
        for (int off = 32; off; off >>= 1) m = fmaxf(m, __shfl_xor(m, off, 64));
        float sum = 0.f;
        for (int j = lane; j < deg; j += 64){
            int sj = csr_src[start + j];
            float v = as[sj] + adv; v = v > 0.f ? v : NEG_SLOPE * v;
            sum += __expf(v - m);
        }
        #pragma unroll
        for (int off = 32; off; off >>= 1) sum += __shfl_xor(sum, off, 64);
        float inv = 1.f / (sum + 1e-16f);
        for (int j = 0; j < deg; j++){
            int sj = csr_src[start + j];                 // broadcast load
            float v = as[sj] + adv; v = v > 0.f ? v : NEG_SLOPE * v;
            float aj = __expf(v - m) * inv;
            const float* hr = h + (long)sj * CO + lane * VPL;
            if (VPL == 2){
                float2 hv = *(const float2*)hr;
                acc[0] += aj * hv.x;
                acc[VPL - 1] += aj * hv.y;
            } else {
                acc[0] += aj * hr[0];
            }
        }
    }

    float* o = out + (long)node * CO + lane * VPL;
    if (VPL == 2){
        float2 ov;
        ov.x = acc[0] + bias[lane * 2];
        ov.y = acc[VPL - 1] + bias[lane * 2 + 1];
        *(float2*)o = ov;
    } else {
        o[0] = acc[0] + bias[lane];
    }
}

extern "C" void kernel_launch(void* const* d_in, const int* in_sizes, int n_in,
                              void* d_out, int out_size, void* d_ws, size_t ws_size,
                              hipStream_t stream)
{
    const float* fea  = (const float*)d_in[0];  // [B,N,128]
    const int*   ei   = (const int*)  d_in[1];  // [B,2,E]
    const float* W1   = (const float*)d_in[2];  // [128,128]
    const float* av_s1= (const float*)d_in[3];  // [1,128]
    const float* av_d1= (const float*)d_in[4];
    const float* b1   = (const float*)d_in[5];  // [128]
    const float* W2   = (const float*)d_in[6];  // [128,64]
    const float* av_s2= (const float*)d_in[7];  // [1,64]
    const float* av_d2= (const float*)d_in[8];
    const float* b2   = (const float*)d_in[9];  // [64]
    float* out = (float*)d_out;

    const int B = 2;
    const int N = out_size / (B * 64);          // 50000
    const int E = in_sizes[1] / (2 * B);        // 800000
    const int Etot = E + N;                     // with self-loops

    // workspace layout
    float* ws = (float*)d_ws;
    size_t off = 0;
    float* h1   = ws + off; off += (size_t)N * 128;
    float* agg1 = ws + off; off += (size_t)N * 128;
    float* h2   = ws + off; off += (size_t)N * 64;
    float* as1  = ws + off; off += N;
    float* ad1  = ws + off; off += N;
    float* as2  = ws + off; off += N;
    float* ad2  = ws + off; off += N;
    int* counts = (int*)(ws + off); off += N;
    int* fill   = (int*)(ws + off); off += N;
    int* scan1b = (int*)(ws + off); off += N;
    int* bsum   = (int*)(ws + off); off += 256;
    int* rowptr = (int*)(ws + off); off += (N + 1);
    int* csrsrc = (int*)(ws + off); off += Etot;
    // total ~17.3M floats (~69 MB)

    const int nb = cdiv(N, 256);

    for (int b = 0; b < B; b++){
        const int* srcp = ei + (size_t)b * 2 * E;
        const int* dstp = srcp + E;
        const float* xb = fea + (size_t)b * N * 128;
        float* outb = out + (size_t)b * N * 64;

        // ---- CSR build (dst-sorted src list), shared by both layers ----
        hipMemsetAsync(counts, 0, (size_t)N * sizeof(int), stream);
        hipMemsetAsync(fill,   0, (size_t)N * sizeof(int), stream);
        count_dst<<<cdiv(Etot, BLK), BLK, 0, stream>>>(dstp, E, Etot, counts);
        scan1_k<<<nb, 256, 0, stream>>>(counts, N, scan1b, bsum);
        scan2_k<<<1, 256, 0, stream>>>(bsum, nb);
        scan3_k<<<nb, 256, 0, stream>>>(counts, scan1b, bsum, N, Etot, rowptr);
        scatter_src<<<cdiv(Etot, BLK), BLK, 0, stream>>>(srcp, dstp, E, Etot, rowptr, fill, csrsrc);

        // ---- layer 1 ----
        {
            long th = (long)((N + 3) / 4) * 32;
            gemm_att<128,false><<<cdiv(th, BLK), BLK, 0, stream>>>(xb, W1, av_s1, av_d1, h1, as1, ad1, N);
        }
        node_agg<128><<<cdiv(N, BLK/64), BLK, 0, stream>>>(rowptr, csrsrc, as1, ad1, h1, b1, agg1, N);

        // ---- layer 2 (input = relu(agg1), agg1 already includes b1) ----
        {
            long th = (long)((N + 3) / 4) * 16;
            gemm_att<64,true><<<cdiv(th, BLK), BLK, 0, stream>>>(agg1, W2, av_s2, av_d2, h2, as2, ad2, N);
        }
        node_agg<64><<<cdiv(N, BLK/64), BLK, 0, stream>>>(rowptr, csrsrc, as2, ad2, h2, b2, outb, N);
    }
}

// Round 3
// 561.370 us; speedup vs baseline: 8.6186x; 1.1099x over previous
//
#include <hip/hip_runtime.h>

#define NEG_SLOPE 0.2f
static constexpr int BLK = 256;

static inline int cdiv(long a, long b){ return (int)((a + b - 1) / b); }

// ------------------- GEMM + attention dots -------------------
// H = X @ W   (X: [N,128], W: [128,CO]); also as_out[n] = H[n,:]·avs, ad_out[n] = H[n,:]·avd
template<int CO, bool RELU_IN>
__global__ __launch_bounds__(BLK) void gemm_att(
    const float* __restrict__ X, const float* __restrict__ W,
    const float* __restrict__ avs, const float* __restrict__ avd,
    float* __restrict__ H, float* __restrict__ as_out, float* __restrict__ ad_out,
    int N)
{
    constexpr int TPR = CO / 4;   // threads per 4-row group (32 or 16)
    long gid = (long)blockIdx.x * BLK + threadIdx.x;
    int group = (int)(gid / TPR);
    int sub   = (int)(gid % TPR);
    int r0 = group * 4;
    if (r0 >= N) return;
    int c0 = sub * 4;

    const float* xr[4];
    #pragma unroll
    for (int i = 0; i < 4; i++) xr[i] = X + (long)min(r0 + i, N - 1) * 128;

    float4 acc[4];
    #pragma unroll
    for (int i = 0; i < 4; i++) acc[i] = make_float4(0.f, 0.f, 0.f, 0.f);

    #pragma unroll 2
    for (int k4 = 0; k4 < 32; k4++){
        float xs[4][4];
        #pragma unroll
        for (int i = 0; i < 4; i++){
            float4 xv = *(const float4*)(xr[i] + k4 * 4);
            if (RELU_IN){
                xv.x = fmaxf(xv.x, 0.f); xv.y = fmaxf(xv.y, 0.f);
                xv.z = fmaxf(xv.z, 0.f); xv.w = fmaxf(xv.w, 0.f);
            }
            xs[i][0] = xv.x; xs[i][1] = xv.y; xs[i][2] = xv.z; xs[i][3] = xv.w;
        }
        #pragma unroll
        for (int kk = 0; kk < 4; kk++){
            float4 w = *(const float4*)(W + (k4 * 4 + kk) * CO + c0);
            #pragma unroll
            for (int i = 0; i < 4; i++){
                acc[i].x += xs[i][kk] * w.x;
                acc[i].y += xs[i][kk] * w.y;
                acc[i].z += xs[i][kk] * w.z;
                acc[i].w += xs[i][kk] * w.w;
            }
        }
    }

    float4 vs4 = *(const float4*)(avs + c0);
    float4 vd4 = *(const float4*)(avd + c0);
    float ssum[4], dsum[4];
    #pragma unroll
    for (int i = 0; i < 4; i++){
        ssum[i] = acc[i].x*vs4.x + acc[i].y*vs4.y + acc[i].z*vs4.z + acc[i].w*vs4.w;
        dsum[i] = acc[i].x*vd4.x + acc[i].y*vd4.y + acc[i].z*vd4.z + acc[i].w*vd4.w;
        if (r0 + i < N) *(float4*)(H + (long)(r0 + i) * CO + c0) = acc[i];
    }
    #pragma unroll
    for (int off = TPR >> 1; off > 0; off >>= 1){
        #pragma unroll
        for (int i = 0; i < 4; i++){
            ssum[i] += __shfl_xor(ssum[i], off, 64);
            dsum[i] += __shfl_xor(dsum[i], off, 64);
        }
    }
    if (sub == 0){
        #pragma unroll
        for (int i = 0; i < 4; i++){
            if (r0 + i < N){ as_out[r0 + i] = ssum[i]; ad_out[r0 + i] = dsum[i]; }
        }
    }
}

// ------------------- CSR build (per graph; shared by both layers) -------------------
__global__ __launch_bounds__(BLK) void count_dst(
    const int* __restrict__ dst, int E, int Etot, int* __restrict__ counts)
{
    int e = blockIdx.x * BLK + threadIdx.x;
    if (e >= Etot) return;
    int d = (e < E) ? dst[e] : (e - E);
    atomicAdd(counts + d, 1);
}

__global__ __launch_bounds__(256) void scan1_k(
    const int* __restrict__ counts, int N, int* __restrict__ scan1, int* __restrict__ bsum)
{
    __shared__ int sh[256];
    int i = blockIdx.x * 256 + threadIdx.x;
    int v = (i < N) ? counts[i] : 0;
    sh[threadIdx.x] = v;
    __syncthreads();
    #pragma unroll
    for (int off = 1; off < 256; off <<= 1){
        int t = (threadIdx.x >= off) ? sh[threadIdx.x - off] : 0;
        __syncthreads();
        sh[threadIdx.x] += t;
        __syncthreads();
    }
    if (i < N) scan1[i] = sh[threadIdx.x];
    if (threadIdx.x == 255) bsum[blockIdx.x] = sh[255];
}

__global__ __launch_bounds__(256) void scan2_k(int* __restrict__ bsum, int nb)
{
    __shared__ int sh[256];
    int v = (threadIdx.x < nb) ? bsum[threadIdx.x] : 0;
    sh[threadIdx.x] = v;
    __syncthreads();
    #pragma unroll
    for (int off = 1; off < 256; off <<= 1){
        int t = (threadIdx.x >= off) ? sh[threadIdx.x - off] : 0;
        __syncthreads();
        sh[threadIdx.x] += t;
        __syncthreads();
    }
    if (threadIdx.x < nb) bsum[threadIdx.x] = sh[threadIdx.x] - v;  // exclusive
}

__global__ __launch_bounds__(256) void scan3_k(
    const int* __restrict__ counts, const int* __restrict__ scan1,
    const int* __restrict__ bsum, int N, int Etot, int* __restrict__ rowptr)
{
    int i = blockIdx.x * 256 + threadIdx.x;
    if (i < N) rowptr[i] = scan1[i] - counts[i] + bsum[blockIdx.x];
    if (i == 0) rowptr[N] = Etot;
}

__global__ __launch_bounds__(BLK) void scatter_src(
    const int* __restrict__ src, const int* __restrict__ dst, int E, int Etot,
    const int* __restrict__ rowptr, int* __restrict__ fill, int* __restrict__ csr_src)
{
    int e = blockIdx.x * BLK + threadIdx.x;
    if (e >= Etot) return;
    int s, d;
    if (e < E){ s = src[e]; d = dst[e]; } else { s = e - E; d = s; }
    int pos = rowptr[d] + atomicAdd(fill + d, 1);
    csr_src[pos] = s;
}

// ------------------- fused softmax + aggregation, one wave per dst node ------------
// Aggregation runs in half-wave mode: lanes 0-31 and 32-63 process different edges,
// each half reads a full h-row with vector loads (float4 for CO=128, float2 for CO=64).
// Unrolled x2 -> 4 independent row loads in flight per wave.
template<int CO>
__global__ __launch_bounds__(BLK) void node_agg(
    const int* __restrict__ rowptr, const int* __restrict__ csr_src,
    const float* __restrict__ as, const float* __restrict__ ad,
    const float* __restrict__ h, const float* __restrict__ bias,
    float* __restrict__ out, int N)
{
    constexpr int V = CO / 32;     // floats per lane in half-wave mode (4 or 2)
    int node = blockIdx.x * (BLK / 64) + (threadIdx.x >> 6);
    int lane = threadIdx.x & 63;
    if (node >= N) return;
    int start = rowptr[node];
    int deg   = rowptr[node + 1] - start;
    float adv = ad[node];
    int half = lane >> 5;
    int hl   = lane & 31;

    if (deg <= 64){
        int   s = 0;
        float e = -1e30f;
        if (lane < deg){
            s = csr_src[start + lane];
            float v = as[s] + adv;
            e = v > 0.f ? v : NEG_SLOPE * v;
        }
        float m = e;
        #pragma unroll
        for (int off = 32; off; off >>= 1) m = fmaxf(m, __shfl_xor(m, off, 64));
        float ex = (lane < deg) ? __expf(e - m) : 0.f;
        float sum = ex;
        #pragma unroll
        for (int off = 32; off; off >>= 1) sum += __shfl_xor(sum, off, 64);
        float alpha = ex / (sum + 1e-16f);

        float acc[V];
        #pragma unroll
        for (int i = 0; i < V; i++) acc[i] = 0.f;

        int j = 0;
        for (; j + 3 < deg; j += 4){
            int e0 = j + half, e1 = j + 2 + half;
            int   s0 = __shfl(s, e0, 64),      s1 = __shfl(s, e1, 64);
            float a0 = __shfl(alpha, e0, 64),  a1 = __shfl(alpha, e1, 64);
            const float* r0p = h + (long)s0 * CO + hl * V;
            const float* r1p = h + (long)s1 * CO + hl * V;
            if (V == 4){
                float4 h0 = *(const float4*)r0p;
                float4 h1 = *(const float4*)r1p;
                acc[0]   += a0 * h0.x + a1 * h1.x;
                acc[1]   += a0 * h0.y + a1 * h1.y;
                acc[2]   += a0 * h0.z + a1 * h1.z;
                acc[V-1] += a0 * h0.w + a1 * h1.w;
            } else {
                float2 h0 = *(const float2*)r0p;
                float2 h1 = *(const float2*)r1p;
                acc[0]   += a0 * h0.x + a1 * h1.x;
                acc[V-1] += a0 * h0.y + a1 * h1.y;
            }
        }
        for (; j + 1 < deg; j += 2){
            int e0 = j + half;
            int   s0 = __shfl(s, e0, 64);
            float a0 = __shfl(alpha, e0, 64);
            const float* r0p = h + (long)s0 * CO + hl * V;
            if (V == 4){
                float4 h0 = *(const float4*)r0p;
                acc[0] += a0 * h0.x; acc[1] += a0 * h0.y;
                acc[2] += a0 * h0.z; acc[V-1] += a0 * h0.w;
            } else {
                float2 h0 = *(const float2*)r0p;
                acc[0] += a0 * h0.x; acc[V-1] += a0 * h0.y;
            }
        }
        if (j < deg){
            int   s0 = __shfl(s, j, 64);
            float a0 = __shfl(alpha, j, 64);
            if (half == 0){
                const float* r0p = h + (long)s0 * CO + hl * V;
                if (V == 4){
                    float4 h0 = *(const float4*)r0p;
                    acc[0] += a0 * h0.x; acc[1] += a0 * h0.y;
                    acc[2] += a0 * h0.z; acc[V-1] += a0 * h0.w;
                } else {
                    float2 h0 = *(const float2*)r0p;
                    acc[0] += a0 * h0.x; acc[V-1] += a0 * h0.y;
                }
            }
        }
        // combine the two halves, lanes 0-31 write the row
        #pragma unroll
        for (int i = 0; i < V; i++) acc[i] += __shfl_xor(acc[i], 32, 64);
        if (half == 0){
            float* o = out + (long)node * CO + hl * V;
            if (V == 4){
                float4 ov;
                ov.x = acc[0]   + bias[hl * 4 + 0];
                ov.y = acc[1]   + bias[hl * 4 + 1];
                ov.z = acc[2]   + bias[hl * 4 + 2];
                ov.w = acc[V-1] + bias[hl * 4 + 3];
                *(float4*)o = ov;
            } else {
                float2 ov;
                ov.x = acc[0]   + bias[hl * 2 + 0];
                ov.y = acc[V-1] + bias[hl * 2 + 1];
                *(float2*)o = ov;
            }
        }
    } else {
        // rare fallback for deg > 64: full-wave, VPL floats per lane
        constexpr int VPL = CO / 64;
        float accf[VPL];
        #pragma unroll
        for (int i = 0; i < VPL; i++) accf[i] = 0.f;
        float m = -1e30f;
        for (int j = lane; j < deg; j += 64){
            int sj = csr_src[start + j];
            float v = as[sj] + adv; v = v > 0.f ? v : NEG_SLOPE * v;
            m = fmaxf(m, v);
        }
        #pragma unroll
        for (int off = 32; off; off >>= 1) m = fmaxf(m, __shfl_xor(m, off, 64));
        float sum = 0.f;
        for (int j = lane; j < deg; j += 64){
            int sj = csr_src[start + j];
            float v = as[sj] + adv; v = v > 0.f ? v : NEG_SLOPE * v;
            sum += __expf(v - m);
        }
        #pragma unroll
        for (int off = 32; off; off >>= 1) sum += __shfl_xor(sum, off, 64);
        float inv = 1.f / (sum + 1e-16f);
        for (int j = 0; j < deg; j++){
            int sj = csr_src[start + j];
            float v = as[sj] + adv; v = v > 0.f ? v : NEG_SLOPE * v;
            float aj = __expf(v - m) * inv;
            const float* hr = h + (long)sj * CO + lane * VPL;
            if (VPL == 2){
                float2 hv = *(const float2*)hr;
                accf[0] += aj * hv.x;
                accf[VPL-1] += aj * hv.y;
            } else {
                accf[0] += aj * hr[0];
            }
        }
        float* o = out + (long)node * CO + lane * VPL;
        if (VPL == 2){
            float2 ov;
            ov.x = accf[0] + bias[lane * 2];
            ov.y = accf[VPL-1] + bias[lane * 2 + 1];
            *(float2*)o = ov;
        } else {
            o[0] = accf[0] + bias[lane];
        }
    }
}

extern "C" void kernel_launch(void* const* d_in, const int* in_sizes, int n_in,
                              void* d_out, int out_size, void* d_ws, size_t ws_size,
                              hipStream_t stream)
{
    const float* fea  = (const float*)d_in[0];  // [B,N,128]
    const int*   ei   = (const int*)  d_in[1];  // [B,2,E]
    const float* W1   = (const float*)d_in[2];  // [128,128]
    const float* av_s1= (const float*)d_in[3];  // [1,128]
    const float* av_d1= (const float*)d_in[4];
    const float* b1   = (const float*)d_in[5];  // [128]
    const float* W2   = (const float*)d_in[6];  // [128,64]
    const float* av_s2= (const float*)d_in[7];  // [1,64]
    const float* av_d2= (const float*)d_in[8];
    const float* b2   = (const float*)d_in[9];  // [64]
    float* out = (float*)d_out;

    const int B = 2;
    const int N = out_size / (B * 64);          // 50000
    const int E = in_sizes[1] / (2 * B);        // 800000
    const int Etot = E + N;                     // with self-loops

    // workspace layout
    float* ws = (float*)d_ws;
    size_t off = 0;
    float* h1   = ws + off; off += (size_t)N * 128;
    float* agg1 = ws + off; off += (size_t)N * 128;
    float* h2   = ws + off; off += (size_t)N * 64;
    float* as1  = ws + off; off += N;
    float* ad1  = ws + off; off += N;
    float* as2  = ws + off; off += N;
    float* ad2  = ws + off; off += N;
    int* counts = (int*)(ws + off); off += N;
    int* fill   = (int*)(ws + off); off += N;   // contiguous with counts (one memset)
    int* scan1b = (int*)(ws + off); off += N;
    int* bsum   = (int*)(ws + off); off += 256;
    int* rowptr = (int*)(ws + off); off += (N + 1);
    int* csrsrc = (int*)(ws + off); off += Etot;

    const int nb = cdiv(N, 256);

    for (int b = 0; b < B; b++){
        const int* srcp = ei + (size_t)b * 2 * E;
        const int* dstp = srcp + E;
        const float* xb = fea + (size_t)b * N * 128;
        float* outb = out + (size_t)b * N * 64;

        // ---- CSR build (dst-sorted src list), shared by both layers ----
        hipMemsetAsync(counts, 0, (size_t)2 * N * sizeof(int), stream);  // counts + fill
        count_dst<<<cdiv(Etot, BLK), BLK, 0, stream>>>(dstp, E, Etot, counts);
        scan1_k<<<nb, 256, 0, stream>>>(counts, N, scan1b, bsum);
        scan2_k<<<1, 256, 0, stream>>>(bsum, nb);
        scan3_k<<<nb, 256, 0, stream>>>(counts, scan1b, bsum, N, Etot, rowptr);
        scatter_src<<<cdiv(Etot, BLK), BLK, 0, stream>>>(srcp, dstp, E, Etot, rowptr, fill, csrsrc);

        // ---- layer 1 ----
        {
            long th = (long)((N + 3) / 4) * 32;
            gemm_att<128,false><<<cdiv(th, BLK), BLK, 0, stream>>>(xb, W1, av_s1, av_d1, h1, as1, ad1, N);
        }
        node_agg<128><<<cdiv(N, BLK/64), BLK, 0, stream>>>(rowptr, csrsrc, as1, ad1, h1, b1, agg1, N);

        // ---- layer 2 (input = relu(agg1), agg1 already includes b1) ----
        {
            long th = (long)((N + 3) / 4) * 16;
            gemm_att<64,true><<<cdiv(th, BLK), BLK, 0, stream>>>(agg1, W2, av_s2, av_d2, h2, as2, ad2, N);
        }
        node_agg<64><<<cdiv(N, BLK/64), BLK, 0, stream>>>(rowptr, csrsrc, as2, ad2, h2, b2, outb, N);
    }
}

// Round 4
// 512.430 us; speedup vs baseline: 9.4418x; 1.0955x over previous
//
#include <hip/hip_runtime.h>

#define NEG_SLOPE 0.2f
static constexpr int BLK = 256;

typedef short bf16x8 __attribute__((ext_vector_type(8)));
typedef float f32x4  __attribute__((ext_vector_type(4)));

static inline int cdiv(long a, long b){ return (int)((a + b - 1) / b); }

__device__ __forceinline__ unsigned short f2bf(float f){
    unsigned u = __float_as_uint(f);
    u += 0x7fff + ((u >> 16) & 1);          // round-to-nearest-even
    return (unsigned short)(u >> 16);
}
__device__ __forceinline__ float bf2f(unsigned short h){
    return __uint_as_float(((unsigned)h) << 16);
}

// ------------------- W prep: transpose + split into bf16 hi/lo -------------------
// Wt[c*K + k] = W[k*CO + c], K=128
__global__ __launch_bounds__(BLK) void prep_w(
    const float* __restrict__ W, int CO,
    unsigned short* __restrict__ Wt_hi, unsigned short* __restrict__ Wt_lo)
{
    int i = blockIdx.x * BLK + threadIdx.x;
    if (i >= CO * 128) return;
    int c = i >> 7, k = i & 127;
    float w = W[k * CO + c];
    unsigned short hi = f2bf(w);
    Wt_hi[i] = hi;
    Wt_lo[i] = f2bf(w - bf2f(hi));
}

// ------------------- MFMA GEMM + attention dots -------------------
// H = X @ W (X:[N,128] f32, W via Wt_hi/lo [CO][128] bf16). One wave per 16 rows.
// Split-bf16: x*w = xh*wh + xh*wl + xl*wh (exact to ~2^-18).
// as_out[n] = H[n,:]·avs, ad_out[n] = H[n,:]·avd.
template<int CO, bool RELU_IN>
__global__ __launch_bounds__(256) void gemm_mfma(
    const float* __restrict__ X,
    const unsigned short* __restrict__ Wt_hi,
    const unsigned short* __restrict__ Wt_lo,
    const float* __restrict__ avs, const float* __restrict__ avd,
    float* __restrict__ H, float* __restrict__ as_out, float* __restrict__ ad_out,
    int N)
{
    constexpr int CT = CO / 16;
    int wave = threadIdx.x >> 6;
    int lane = threadIdx.x & 63;
    int r0 = (blockIdx.x * 4 + wave) * 16;
    if (r0 >= N) return;               // 16 | N, so live waves are fully in-bounds
    int rl = lane & 15;                // A-row / B-col / D-col within tile
    int g  = lane >> 4;                // k-group (8 consecutive k per lane)

    const float* xrow = X + (long)(r0 + rl) * 128 + g * 8;

    f32x4 acc[CT];
    #pragma unroll
    for (int t = 0; t < CT; t++) acc[t] = (f32x4)(0.f);

    #pragma unroll
    for (int ks = 0; ks < 4; ks++){
        float4 xa = *(const float4*)(xrow + ks * 32);
        float4 xb = *(const float4*)(xrow + ks * 32 + 4);
        float xv[8] = {xa.x, xa.y, xa.z, xa.w, xb.x, xb.y, xb.z, xb.w};
        bf16x8 ahi, alo;
        #pragma unroll
        for (int j = 0; j < 8; j++){
            float x = xv[j];
            if (RELU_IN) x = fmaxf(x, 0.f);
            unsigned short h = f2bf(x);
            ahi[j] = (short)h;
            alo[j] = (short)f2bf(x - bf2f(h));
        }
        #pragma unroll
        for (int t = 0; t < CT; t++){
            long boff = (long)(t * 16 + rl) * 128 + ks * 32 + g * 8;
            bf16x8 bhi = *(const bf16x8*)(Wt_hi + boff);
            bf16x8 blo = *(const bf16x8*)(Wt_lo + boff);
            acc[t] = __builtin_amdgcn_mfma_f32_16x16x32_bf16(ahi, bhi, acc[t], 0, 0, 0);
            acc[t] = __builtin_amdgcn_mfma_f32_16x16x32_bf16(ahi, blo, acc[t], 0, 0, 0);
            acc[t] = __builtin_amdgcn_mfma_f32_16x16x32_bf16(alo, bhi, acc[t], 0, 0, 0);
        }
    }

    // epilogue: store H (f32) and compute as/ad via in-register partials
    float ps[4] = {0.f, 0.f, 0.f, 0.f}, pd[4] = {0.f, 0.f, 0.f, 0.f};
    #pragma unroll
    for (int t = 0; t < CT; t++){
        float vs = avs[t * 16 + rl], vd = avd[t * 16 + rl];
        #pragma unroll
        for (int r = 0; r < 4; r++){
            float hv = acc[t][r];
            ps[r] += hv * vs;
            pd[r] += hv * vd;
            H[(long)(r0 + 4 * g + r) * CO + t * 16 + rl] = hv;
        }
    }
    // reduce over the 16 lanes (cols) within each k-group
    #pragma unroll
    for (int off = 1; off < 16; off <<= 1){
        #pragma unroll
        for (int r = 0; r < 4; r++){
            ps[r] += __shfl_xor(ps[r], off, 64);
            pd[r] += __shfl_xor(pd[r], off, 64);
        }
    }
    if (rl == 0){
        #pragma unroll
        for (int r = 0; r < 4; r++){
            as_out[r0 + 4 * g + r] = ps[r];
            ad_out[r0 + 4 * g + r] = pd[r];
        }
    }
}

// ------------------- CSR build (per graph; shared by both layers) -------------------
__global__ __launch_bounds__(BLK) void count_dst(
    const int* __restrict__ dst, int E, int Etot, int* __restrict__ counts)
{
    int e = blockIdx.x * BLK + threadIdx.x;
    if (e >= Etot) return;
    int d = (e < E) ? dst[e] : (e - E);
    atomicAdd(counts + d, 1);
}

__global__ __launch_bounds__(256) void scan1_k(
    const int* __restrict__ counts, int N, int* __restrict__ scan1, int* __restrict__ bsum)
{
    __shared__ int sh[256];
    int i = blockIdx.x * 256 + threadIdx.x;
    int v = (i < N) ? counts[i] : 0;
    sh[threadIdx.x] = v;
    __syncthreads();
    #pragma unroll
    for (int off = 1; off < 256; off <<= 1){
        int t = (threadIdx.x >= off) ? sh[threadIdx.x - off] : 0;
        __syncthreads();
        sh[threadIdx.x] += t;
        __syncthreads();
    }
    if (i < N) scan1[i] = sh[threadIdx.x];
    if (threadIdx.x == 255) bsum[blockIdx.x] = sh[255];
}

__global__ __launch_bounds__(256) void scan2_k(int* __restrict__ bsum, int nb)
{
    __shared__ int sh[256];
    int v = (threadIdx.x < nb) ? bsum[threadIdx.x] : 0;
    sh[threadIdx.x] = v;
    __syncthreads();
    #pragma unroll
    for (int off = 1; off < 256; off <<= 1){
        int t = (threadIdx.x >= off) ? sh[threadIdx.x - off] : 0;
        __syncthreads();
        sh[threadIdx.x] += t;
        __syncthreads();
    }
    if (threadIdx.x < nb) bsum[threadIdx.x] = sh[threadIdx.x] - v;  // exclusive
}

__global__ __launch_bounds__(256) void scan3_k(
    const int* __restrict__ counts, const int* __restrict__ scan1,
    const int* __restrict__ bsum, int N, int Etot, int* __restrict__ rowptr)
{
    int i = blockIdx.x * 256 + threadIdx.x;
    if (i < N) rowptr[i] = scan1[i] - counts[i] + bsum[blockIdx.x];
    if (i == 0) rowptr[N] = Etot;
}

__global__ __launch_bounds__(BLK) void scatter_src(
    const int* __restrict__ src, const int* __restrict__ dst, int E, int Etot,
    const int* __restrict__ rowptr, int* __restrict__ fill, int* __restrict__ csr_src)
{
    int e = blockIdx.x * BLK + threadIdx.x;
    if (e >= Etot) return;
    int s, d;
    if (e < E){ s = src[e]; d = dst[e]; } else { s = e - E; d = s; }
    int pos = rowptr[d] + atomicAdd(fill + d, 1);
    csr_src[pos] = s;
}

// ------------------- fused softmax + aggregation, one wave per dst node ------------
template<int CO>
__global__ __launch_bounds__(BLK) void node_agg(
    const int* __restrict__ rowptr, const int* __restrict__ csr_src,
    const float* __restrict__ as, const float* __restrict__ ad,
    const float* __restrict__ h, const float* __restrict__ bias,
    float* __restrict__ out, int N)
{
    constexpr int V = CO / 32;     // floats per lane in half-wave mode (4 or 2)
    int node = blockIdx.x * (BLK / 64) + (threadIdx.x >> 6);
    int lane = threadIdx.x & 63;
    if (node >= N) return;
    int start = rowptr[node];
    int deg   = rowptr[node + 1] - start;
    float adv = ad[node];
    int half = lane >> 5;
    int hl   = lane & 31;

    if (deg <= 64){
        int   s = 0;
        float e = -1e30f;
        if (lane < deg){
            s = csr_src[start + lane];
            float v = as[s] + adv;
            e = v > 0.f ? v : NEG_SLOPE * v;
        }
        float m = e;
        #pragma unroll
        for (int off = 32; off; off >>= 1) m = fmaxf(m, __shfl_xor(m, off, 64));
        float ex = (lane < deg) ? __expf(e - m) : 0.f;
        float sum = ex;
        #pragma unroll
        for (int off = 32; off; off >>= 1) sum += __shfl_xor(sum, off, 64);
        float alpha = ex / (sum + 1e-16f);

        float acc[V];
        #pragma unroll
        for (int i = 0; i < V; i++) acc[i] = 0.f;

        int j = 0;
        for (; j + 3 < deg; j += 4){
            int e0 = j + half, e1 = j + 2 + half;
            int   s0 = __shfl(s, e0, 64),      s1 = __shfl(s, e1, 64);
            float a0 = __shfl(alpha, e0, 64),  a1 = __shfl(alpha, e1, 64);
            const float* r0p = h + (long)s0 * CO + hl * V;
            const float* r1p = h + (long)s1 * CO + hl * V;
            if (V == 4){
                float4 h0 = *(const float4*)r0p;
                float4 h1 = *(const float4*)r1p;
                acc[0]   += a0 * h0.x + a1 * h1.x;
                acc[1]   += a0 * h0.y + a1 * h1.y;
                acc[2]   += a0 * h0.z + a1 * h1.z;
                acc[V-1] += a0 * h0.w + a1 * h1.w;
            } else {
                float2 h0 = *(const float2*)r0p;
                float2 h1 = *(const float2*)r1p;
                acc[0]   += a0 * h0.x + a1 * h1.x;
                acc[V-1] += a0 * h0.y + a1 * h1.y;
            }
        }
        for (; j + 1 < deg; j += 2){
            int e0 = j + half;
            int   s0 = __shfl(s, e0, 64);
            float a0 = __shfl(alpha, e0, 64);
            const float* r0p = h + (long)s0 * CO + hl * V;
            if (V == 4){
                float4 h0 = *(const float4*)r0p;
                acc[0] += a0 * h0.x; acc[1] += a0 * h0.y;
                acc[2] += a0 * h0.z; acc[V-1] += a0 * h0.w;
            } else {
                float2 h0 = *(const float2*)r0p;
                acc[0] += a0 * h0.x; acc[V-1] += a0 * h0.y;
            }
        }
        if (j < deg){
            int   s0 = __shfl(s, j, 64);
            float a0 = __shfl(alpha, j, 64);
            if (half == 0){
                const float* r0p = h + (long)s0 * CO + hl * V;
                if (V == 4){
                    float4 h0 = *(const float4*)r0p;
                    acc[0] += a0 * h0.x; acc[1] += a0 * h0.y;
                    acc[2] += a0 * h0.z; acc[V-1] += a0 * h0.w;
                } else {
                    float2 h0 = *(const float2*)r0p;
                    acc[0] += a0 * h0.x; acc[V-1] += a0 * h0.y;
                }
            }
        }
        #pragma unroll
        for (int i = 0; i < V; i++) acc[i] += __shfl_xor(acc[i], 32, 64);
        if (half == 0){
            float* o = out + (long)node * CO + hl * V;
            if (V == 4){
                float4 ov;
                ov.x = acc[0]   + bias[hl * 4 + 0];
                ov.y = acc[1]   + bias[hl * 4 + 1];
                ov.z = acc[2]   + bias[hl * 4 + 2];
                ov.w = acc[V-1] + bias[hl * 4 + 3];
                *(float4*)o = ov;
            } else {
                float2 ov;
                ov.x = acc[0]   + bias[hl * 2 + 0];
                ov.y = acc[V-1] + bias[hl * 2 + 1];
                *(float2*)o = ov;
            }
        }
    } else {
        constexpr int VPL = CO / 64;
        float accf[VPL];
        #pragma unroll
        for (int i = 0; i < VPL; i++) accf[i] = 0.f;
        float m = -1e30f;
        for (int j = lane; j < deg; j += 64){
            int sj = csr_src[start + j];
            float v = as[sj] + adv; v = v > 0.f ? v : NEG_SLOPE * v;
            m = fmaxf(m, v);
        }
        #pragma unroll
        for (int off = 32; off; off >>= 1) m = fmaxf(m, __shfl_xor(m, off, 64));
        float sum = 0.f;
        for (int j = lane; j < deg; j += 64){
            int sj = csr_src[start + j];
            float v = as[sj] + adv; v = v > 0.f ? v : NEG_SLOPE * v;
            sum += __expf(v - m);
        }
        #pragma unroll
        for (int off = 32; off; off >>= 1) sum += __shfl_xor(sum, off, 64);
        float inv = 1.f / (sum + 1e-16f);
        for (int j = 0; j < deg; j++){
            int sj = csr_src[start + j];
            float v = as[sj] + adv; v = v > 0.f ? v : NEG_SLOPE * v;
            float aj = __expf(v - m) * inv;
            const float* hr = h + (long)sj * CO + lane * VPL;
            if (VPL == 2){
                float2 hv = *(const float2*)hr;
                accf[0] += aj * hv.x;
                accf[VPL-1] += aj * hv.y;
            } else {
                accf[0] += aj * hr[0];
            }
        }
        float* o = out + (long)node * CO + lane * VPL;
        if (VPL == 2){
            float2 ov;
            ov.x = accf[0] + bias[lane * 2];
            ov.y = accf[VPL-1] + bias[lane * 2 + 1];
            *(float2*)o = ov;
        } else {
            o[0] = accf[0] + bias[lane];
        }
    }
}

extern "C" void kernel_launch(void* const* d_in, const int* in_sizes, int n_in,
                              void* d_out, int out_size, void* d_ws, size_t ws_size,
                              hipStream_t stream)
{
    const float* fea  = (const float*)d_in[0];  // [B,N,128]
    const int*   ei   = (const int*)  d_in[1];  // [B,2,E]
    const float* W1   = (const float*)d_in[2];  // [128,128]
    const float* av_s1= (const float*)d_in[3];  // [1,128]
    const float* av_d1= (const float*)d_in[4];
    const float* b1   = (const float*)d_in[5];  // [128]
    const float* W2   = (const float*)d_in[6];  // [128,64]
    const float* av_s2= (const float*)d_in[7];  // [1,64]
    const float* av_d2= (const float*)d_in[8];
    const float* b2   = (const float*)d_in[9];  // [64]
    float* out = (float*)d_out;

    const int B = 2;
    const int N = out_size / (B * 64);          // 50000
    const int E = in_sizes[1] / (2 * B);        // 800000
    const int Etot = E + N;                     // with self-loops

    // workspace layout
    float* ws = (float*)d_ws;
    size_t off = 0;
    float* h1   = ws + off; off += (size_t)N * 128;
    float* agg1 = ws + off; off += (size_t)N * 128;
    float* h2   = ws + off; off += (size_t)N * 64;
    float* as1  = ws + off; off += N;
    float* ad1  = ws + off; off += N;
    float* as2  = ws + off; off += N;
    float* ad2  = ws + off; off += N;
    int* counts = (int*)(ws + off); off += N;
    int* fill   = (int*)(ws + off); off += N;   // contiguous with counts (one memset)
    int* scan1b = (int*)(ws + off); off += N;
    int* bsum   = (int*)(ws + off); off += 256;
    int* rowptr = (int*)(ws + off); off += (N + 1);
    int* csrsrc = (int*)(ws + off); off += Etot;
    unsigned short* wt1h = (unsigned short*)(ws + off); off += 128*128/2;
    unsigned short* wt1l = (unsigned short*)(ws + off); off += 128*128/2;
    unsigned short* wt2h = (unsigned short*)(ws + off); off += 64*128/2;
    unsigned short* wt2l = (unsigned short*)(ws + off); off += 64*128/2;

    const int nb = cdiv(N, 256);

    // W prep (shared by both graphs)
    prep_w<<<cdiv(128*128, BLK), BLK, 0, stream>>>(W1, 128, wt1h, wt1l);
    prep_w<<<cdiv(64*128,  BLK), BLK, 0, stream>>>(W2, 64,  wt2h, wt2l);

    for (int b = 0; b < B; b++){
        const int* srcp = ei + (size_t)b * 2 * E;
        const int* dstp = srcp + E;
        const float* xb = fea + (size_t)b * N * 128;
        float* outb = out + (size_t)b * N * 64;

        // ---- CSR build (dst-sorted src list), shared by both layers ----
        hipMemsetAsync(counts, 0, (size_t)2 * N * sizeof(int), stream);  // counts + fill
        count_dst<<<cdiv(Etot, BLK), BLK, 0, stream>>>(dstp, E, Etot, counts);
        scan1_k<<<nb, 256, 0, stream>>>(counts, N, scan1b, bsum);
        scan2_k<<<1, 256, 0, stream>>>(bsum, nb);
        scan3_k<<<nb, 256, 0, stream>>>(counts, scan1b, bsum, N, Etot, rowptr);
        scatter_src<<<cdiv(Etot, BLK), BLK, 0, stream>>>(srcp, dstp, E, Etot, rowptr, fill, csrsrc);

        // ---- layer 1 ----
        gemm_mfma<128,false><<<cdiv(N, 64), 256, 0, stream>>>(xb, wt1h, wt1l, av_s1, av_d1, h1, as1, ad1, N);
        node_agg<128><<<cdiv(N, BLK/64), BLK, 0, stream>>>(rowptr, csrsrc, as1, ad1, h1, b1, agg1, N);

        // ---- layer 2 (input = relu(agg1), agg1 already includes b1) ----
        gemm_mfma<64,true><<<cdiv(N, 64), 256, 0, stream>>>(agg1, wt2h, wt2l, av_s2, av_d2, h2, as2, ad2, N);
        node_agg<64><<<cdiv(N, BLK/64), BLK, 0, stream>>>(rowptr, csrsrc, as2, ad2, h2, b2, outb, N);
    }
}

// Round 5
// 458.763 us; speedup vs baseline: 10.5463x; 1.1170x over previous
//
#include <hip/hip_runtime.h>

#define NEG_SLOPE 0.2f
static constexpr int BLK = 256;

typedef short bf16x8 __attribute__((ext_vector_type(8)));
typedef float f32x4  __attribute__((ext_vector_type(4)));
typedef unsigned short u16x8 __attribute__((ext_vector_type(8)));

static inline int cdiv(long a, long b){ return (int)((a + b - 1) / b); }

__device__ __forceinline__ unsigned short f2bf(float f){
    unsigned u = __float_as_uint(f);
    u += 0x7fff + ((u >> 16) & 1);          // round-to-nearest-even
    return (unsigned short)(u >> 16);
}
__device__ __forceinline__ float bf2f(unsigned short h){
    return __uint_as_float(((unsigned)h) << 16);
}

// ------------------- W prep: transpose + split into bf16 hi/lo -------------------
__global__ __launch_bounds__(BLK) void prep_w(
    const float* __restrict__ W, int CO,
    unsigned short* __restrict__ Wt_hi, unsigned short* __restrict__ Wt_lo)
{
    int i = blockIdx.x * BLK + threadIdx.x;
    if (i >= CO * 128) return;
    int c = i >> 7, k = i & 127;
    float w = W[k * CO + c];
    unsigned short hi = f2bf(w);
    Wt_hi[i] = hi;
    Wt_lo[i] = f2bf(w - bf2f(hi));
}

// ------------------- MFMA GEMM + attention dots -------------------
// H = X @ W (X:[N,128] f32). Split-bf16: x*w ~= xh*wh + xh*wl + xl*wh.
// H stored bf16 (BF16OUT) or f32. as/ad computed from f32 accumulators.
template<int CO, bool RELU_IN, bool BF16OUT>
__global__ __launch_bounds__(256) void gemm_mfma(
    const float* __restrict__ X,
    const unsigned short* __restrict__ Wt_hi,
    const unsigned short* __restrict__ Wt_lo,
    const float* __restrict__ avs, const float* __restrict__ avd,
    void* __restrict__ Hout, float* __restrict__ as_out, float* __restrict__ ad_out,
    int N)
{
    constexpr int CT = CO / 16;
    int wave = threadIdx.x >> 6;
    int lane = threadIdx.x & 63;
    int r0 = (blockIdx.x * 4 + wave) * 16;
    if (r0 >= N) return;               // 16 | N
    int rl = lane & 15;
    int g  = lane >> 4;

    const float* xrow = X + (long)(r0 + rl) * 128 + g * 8;

    f32x4 acc[CT];
    #pragma unroll
    for (int t = 0; t < CT; t++) acc[t] = (f32x4)(0.f);

    #pragma unroll
    for (int ks = 0; ks < 4; ks++){
        float4 xa = *(const float4*)(xrow + ks * 32);
        float4 xb = *(const float4*)(xrow + ks * 32 + 4);
        float xv[8] = {xa.x, xa.y, xa.z, xa.w, xb.x, xb.y, xb.z, xb.w};
        bf16x8 ahi, alo;
        #pragma unroll
        for (int j = 0; j < 8; j++){
            float x = xv[j];
            if (RELU_IN) x = fmaxf(x, 0.f);
            unsigned short h = f2bf(x);
            ahi[j] = (short)h;
            alo[j] = (short)f2bf(x - bf2f(h));
        }
        #pragma unroll
        for (int t = 0; t < CT; t++){
            long boff = (long)(t * 16 + rl) * 128 + ks * 32 + g * 8;
            bf16x8 bhi = *(const bf16x8*)(Wt_hi + boff);
            bf16x8 blo = *(const bf16x8*)(Wt_lo + boff);
            acc[t] = __builtin_amdgcn_mfma_f32_16x16x32_bf16(ahi, bhi, acc[t], 0, 0, 0);
            acc[t] = __builtin_amdgcn_mfma_f32_16x16x32_bf16(ahi, blo, acc[t], 0, 0, 0);
            acc[t] = __builtin_amdgcn_mfma_f32_16x16x32_bf16(alo, bhi, acc[t], 0, 0, 0);
        }
    }

    float ps[4] = {0.f, 0.f, 0.f, 0.f}, pd[4] = {0.f, 0.f, 0.f, 0.f};
    #pragma unroll
    for (int t = 0; t < CT; t++){
        float vs = avs[t * 16 + rl], vd = avd[t * 16 + rl];
        #pragma unroll
        for (int r = 0; r < 4; r++){
            float hv = acc[t][r];
            ps[r] += hv * vs;
            pd[r] += hv * vd;
            long idx = (long)(r0 + 4 * g + r) * CO + t * 16 + rl;
            if (BF16OUT) ((unsigned short*)Hout)[idx] = f2bf(hv);
            else         ((float*)Hout)[idx] = hv;
        }
    }
    #pragma unroll
    for (int off = 1; off < 16; off <<= 1){
        #pragma unroll
        for (int r = 0; r < 4; r++){
            ps[r] += __shfl_xor(ps[r], off, 64);
            pd[r] += __shfl_xor(pd[r], off, 64);
        }
    }
    if (rl == 0){
        #pragma unroll
        for (int r = 0; r < 4; r++){
            as_out[r0 + 4 * g + r] = ps[r];
            ad_out[r0 + 4 * g + r] = pd[r];
        }
    }
}

// ------------------- CSR build -------------------
__global__ __launch_bounds__(BLK) void count_dst(
    const int* __restrict__ dst, int E, int Etot, int* __restrict__ counts)
{
    int e = blockIdx.x * BLK + threadIdx.x;
    if (e >= Etot) return;
    int d = (e < E) ? dst[e] : (e - E);
    atomicAdd(counts + d, 1);
}

__global__ __launch_bounds__(256) void scan1_k(
    const int* __restrict__ counts, int N, int* __restrict__ scan1, int* __restrict__ bsum)
{
    __shared__ int sh[256];
    int i = blockIdx.x * 256 + threadIdx.x;
    int v = (i < N) ? counts[i] : 0;
    sh[threadIdx.x] = v;
    __syncthreads();
    #pragma unroll
    for (int off = 1; off < 256; off <<= 1){
        int t = (threadIdx.x >= off) ? sh[threadIdx.x - off] : 0;
        __syncthreads();
        sh[threadIdx.x] += t;
        __syncthreads();
    }
    if (i < N) scan1[i] = sh[threadIdx.x];
    if (threadIdx.x == 255) bsum[blockIdx.x] = sh[255];
}

__global__ __launch_bounds__(256) void scan2_k(int* __restrict__ bsum, int nb)
{
    __shared__ int sh[256];
    int v = (threadIdx.x < nb) ? bsum[threadIdx.x] : 0;
    sh[threadIdx.x] = v;
    __syncthreads();
    #pragma unroll
    for (int off = 1; off < 256; off <<= 1){
        int t = (threadIdx.x >= off) ? sh[threadIdx.x - off] : 0;
        __syncthreads();
        sh[threadIdx.x] += t;
        __syncthreads();
    }
    if (threadIdx.x < nb) bsum[threadIdx.x] = sh[threadIdx.x] - v;  // exclusive
}

__global__ __launch_bounds__(256) void scan3_k(
    const int* __restrict__ counts, const int* __restrict__ scan1,
    const int* __restrict__ bsum, int N, int Etot, int* __restrict__ rowptr)
{
    int i = blockIdx.x * 256 + threadIdx.x;
    if (i < N) rowptr[i] = scan1[i] - counts[i] + bsum[blockIdx.x];
    if (i == 0) rowptr[N] = Etot;
}

__global__ __launch_bounds__(BLK) void scatter_src(
    const int* __restrict__ src, const int* __restrict__ dst, int E, int Etot,
    const int* __restrict__ rowptr, int* __restrict__ fill, int* __restrict__ csr_src)
{
    int e = blockIdx.x * BLK + threadIdx.x;
    if (e >= Etot) return;
    int s, d;
    if (e < E){ s = src[e]; d = dst[e]; } else { s = e - E; d = s; }
    int pos = rowptr[d] + atomicAdd(fill + d, 1);
    csr_src[pos] = s;
}

// ------------------- fused softmax + aggregation, one wave per dst node ------------
// Quarter-wave aggregation: 4 groups of 16 lanes; each group reads one full h-row
// (16 lanes x 16B). x2 unroll -> 8 independent row loads in flight per wave.
// BF16H: h stored as bf16 (row = CO*2 bytes, per-lane 8 bf16); else f32 (per-lane float4).
template<int CO, bool BF16H>
__global__ __launch_bounds__(BLK) void node_agg(
    const int* __restrict__ rowptr, const int* __restrict__ csr_src,
    const float* __restrict__ as, const float* __restrict__ ad,
    const void* __restrict__ h, const float* __restrict__ bias,
    float* __restrict__ out, int N)
{
    constexpr int ELEMS = CO / 16;        // floats per lane in quarter-wave mode (8 or 4)
    int node = blockIdx.x * (BLK / 64) + (threadIdx.x >> 6);
    int lane = threadIdx.x & 63;
    if (node >= N) return;
    int start = rowptr[node];
    int deg   = rowptr[node + 1] - start;
    float adv = ad[node];
    int g  = lane >> 4;                   // quarter-group 0..3
    int ql = lane & 15;

    const unsigned short* hb = (const unsigned short*)h;
    const float*          hf = (const float*)h;

    if (deg <= 64){
        int   s = 0;
        float e = -1e30f;
        if (lane < deg){
            s = csr_src[start + lane];
            float v = as[s] + adv;
            e = v > 0.f ? v : NEG_SLOPE * v;
        }
        float m = e;
        #pragma unroll
        for (int off = 32; off; off >>= 1) m = fmaxf(m, __shfl_xor(m, off, 64));
        float ex = (lane < deg) ? __expf(e - m) : 0.f;
        float sum = ex;
        #pragma unroll
        for (int off = 32; off; off >>= 1) sum += __shfl_xor(sum, off, 64);
        float alpha = ex / (sum + 1e-16f);

        float acc[ELEMS];
        #pragma unroll
        for (int i = 0; i < ELEMS; i++) acc[i] = 0.f;

        int j = 0;
        for (; j + 7 < deg; j += 8){
            int e0 = j + g, e1 = j + 4 + g;
            int   s0 = __shfl(s, e0, 64),      s1 = __shfl(s, e1, 64);
            float a0 = __shfl(alpha, e0, 64),  a1 = __shfl(alpha, e1, 64);
            if (BF16H){
                u16x8 h0 = *(const u16x8*)(hb + (long)s0 * CO + ql * ELEMS);
                u16x8 h1 = *(const u16x8*)(hb + (long)s1 * CO + ql * ELEMS);
                #pragma unroll
                for (int i = 0; i < ELEMS; i++)
                    acc[i] += a0 * bf2f(h0[i]) + a1 * bf2f(h1[i]);
            } else {
                float4 h0 = *(const float4*)(hf + (long)s0 * CO + ql * ELEMS);
                float4 h1 = *(const float4*)(hf + (long)s1 * CO + ql * ELEMS);
                acc[0]       += a0 * h0.x + a1 * h1.x;
                acc[1]       += a0 * h0.y + a1 * h1.y;
                acc[2]       += a0 * h0.z + a1 * h1.z;
                acc[ELEMS-1] += a0 * h0.w + a1 * h1.w;
            }
        }
        for (; j + 3 < deg; j += 4){
            int e0 = j + g;
            int   s0 = __shfl(s, e0, 64);
            float a0 = __shfl(alpha, e0, 64);
            if (BF16H){
                u16x8 h0 = *(const u16x8*)(hb + (long)s0 * CO + ql * ELEMS);
                #pragma unroll
                for (int i = 0; i < ELEMS; i++) acc[i] += a0 * bf2f(h0[i]);
            } else {
                float4 h0 = *(const float4*)(hf + (long)s0 * CO + ql * ELEMS);
                acc[0] += a0 * h0.x; acc[1] += a0 * h0.y;
                acc[2] += a0 * h0.z; acc[ELEMS-1] += a0 * h0.w;
            }
        }
        if (j < deg){
            int rem = deg - j;
            int e0 = min(j + g, deg - 1);
            int   s0 = __shfl(s, e0, 64);
            float a0 = __shfl(alpha, e0, 64);
            if (g < rem){
                if (BF16H){
                    u16x8 h0 = *(const u16x8*)(hb + (long)s0 * CO + ql * ELEMS);
                    #pragma unroll
                    for (int i = 0; i < ELEMS; i++) acc[i] += a0 * bf2f(h0[i]);
                } else {
                    float4 h0 = *(const float4*)(hf + (long)s0 * CO + ql * ELEMS);
                    acc[0] += a0 * h0.x; acc[1] += a0 * h0.y;
                    acc[2] += a0 * h0.z; acc[ELEMS-1] += a0 * h0.w;
                }
            }
        }
        // combine the 4 quarter-groups; lanes 0-15 write the row
        #pragma unroll
        for (int i = 0; i < ELEMS; i++){
            acc[i] += __shfl_xor(acc[i], 16, 64);
            acc[i] += __shfl_xor(acc[i], 32, 64);
        }
        if (g == 0){
            float* o = out + (long)node * CO + ql * ELEMS;
            #pragma unroll
            for (int i = 0; i < ELEMS; i += 4){
                float4 ov;
                ov.x = acc[i+0] + bias[ql * ELEMS + i + 0];
                ov.y = acc[i+1] + bias[ql * ELEMS + i + 1];
                ov.z = acc[i+2] + bias[ql * ELEMS + i + 2];
                ov.w = acc[i+3] + bias[ql * ELEMS + i + 3];
                *(float4*)(o + i) = ov;
            }
        }
    } else {
        // rare fallback deg > 64: full-wave, VPL elems per lane
        constexpr int VPL = CO / 64;
        float accf[VPL];
        #pragma unroll
        for (int i = 0; i < VPL; i++) accf[i] = 0.f;
        float m = -1e30f;
        for (int jj = lane; jj < deg; jj += 64){
            int sj = csr_src[start + jj];
            float v = as[sj] + adv; v = v > 0.f ? v : NEG_SLOPE * v;
            m = fmaxf(m, v);
        }
        #pragma unroll
        for (int off = 32; off; off >>= 1) m = fmaxf(m, __shfl_xor(m, off, 64));
        float sum = 0.f;
        for (int jj = lane; jj < deg; jj += 64){
            int sj = csr_src[start + jj];
            float v = as[sj] + adv; v = v > 0.f ? v : NEG_SLOPE * v;
            sum += __expf(v - m);
        }
        #pragma unroll
        for (int off = 32; off; off >>= 1) sum += __shfl_xor(sum, off, 64);
        float inv = 1.f / (sum + 1e-16f);
        for (int jj = 0; jj < deg; jj++){
            int sj = csr_src[start + jj];
            float v = as[sj] + adv; v = v > 0.f ? v : NEG_SLOPE * v;
            float aj = __expf(v - m) * inv;
            if (BF16H){
                const unsigned short* hr = hb + (long)sj * CO + lane * VPL;
                #pragma unroll
                for (int i = 0; i < VPL; i++) accf[i] += aj * bf2f(hr[i]);
            } else {
                const float* hr = hf + (long)sj * CO + lane * VPL;
                #pragma unroll
                for (int i = 0; i < VPL; i++) accf[i] += aj * hr[i];
            }
        }
        float* o = out + (long)node * CO + lane * VPL;
        #pragma unroll
        for (int i = 0; i < VPL; i++) o[i] = accf[i] + bias[lane * VPL + i];
    }
}

extern "C" void kernel_launch(void* const* d_in, const int* in_sizes, int n_in,
                              void* d_out, int out_size, void* d_ws, size_t ws_size,
                              hipStream_t stream)
{
    const float* fea  = (const float*)d_in[0];  // [B,N,128]
    const int*   ei   = (const int*)  d_in[1];  // [B,2,E]
    const float* W1   = (const float*)d_in[2];  // [128,128]
    const float* av_s1= (const float*)d_in[3];
    const float* av_d1= (const float*)d_in[4];
    const float* b1   = (const float*)d_in[5];
    const float* W2   = (const float*)d_in[6];  // [128,64]
    const float* av_s2= (const float*)d_in[7];
    const float* av_d2= (const float*)d_in[8];
    const float* b2   = (const float*)d_in[9];
    float* out = (float*)d_out;

    const int B = 2;
    const int N = out_size / (B * 64);          // 50000
    const int E = in_sizes[1] / (2 * B);        // 800000
    const int Etot = E + N;

    // workspace layout
    float* ws = (float*)d_ws;
    size_t off = 0;
    unsigned short* h1b = (unsigned short*)(ws + off); off += (size_t)N * 64;  // bf16 [N][128]
    float* agg1 = ws + off; off += (size_t)N * 128;
    float* h2   = ws + off; off += (size_t)N * 64;
    float* as1  = ws + off; off += N;
    float* ad1  = ws + off; off += N;
    float* as2  = ws + off; off += N;
    float* ad2  = ws + off; off += N;
    int* counts = (int*)(ws + off); off += N;
    int* fill   = (int*)(ws + off); off += N;   // contiguous with counts (one memset)
    int* scan1b = (int*)(ws + off); off += N;
    int* bsum   = (int*)(ws + off); off += 256;
    int* rowptr = (int*)(ws + off); off += (N + 1);
    int* csrsrc = (int*)(ws + off); off += Etot;
    unsigned short* wt1h = (unsigned short*)(ws + off); off += 128*128/2;
    unsigned short* wt1l = (unsigned short*)(ws + off); off += 128*128/2;
    unsigned short* wt2h = (unsigned short*)(ws + off); off += 64*128/2;
    unsigned short* wt2l = (unsigned short*)(ws + off); off += 64*128/2;

    const int nb = cdiv(N, 256);

    prep_w<<<cdiv(128*128, BLK), BLK, 0, stream>>>(W1, 128, wt1h, wt1l);
    prep_w<<<cdiv(64*128,  BLK), BLK, 0, stream>>>(W2, 64,  wt2h, wt2l);

    for (int b = 0; b < B; b++){
        const int* srcp = ei + (size_t)b * 2 * E;
        const int* dstp = srcp + E;
        const float* xb = fea + (size_t)b * N * 128;
        float* outb = out + (size_t)b * N * 64;

        // ---- CSR build (dst-sorted src list), shared by both layers ----
        hipMemsetAsync(counts, 0, (size_t)2 * N * sizeof(int), stream);
        count_dst<<<cdiv(Etot, BLK), BLK, 0, stream>>>(dstp, E, Etot, counts);
        scan1_k<<<nb, 256, 0, stream>>>(counts, N, scan1b, bsum);
        scan2_k<<<1, 256, 0, stream>>>(bsum, nb);
        scan3_k<<<nb, 256, 0, stream>>>(counts, scan1b, bsum, N, Etot, rowptr);
        scatter_src<<<cdiv(Etot, BLK), BLK, 0, stream>>>(srcp, dstp, E, Etot, rowptr, fill, csrsrc);

        // ---- layer 1 (h1 in bf16) ----
        gemm_mfma<128,false,true><<<cdiv(N, 64), 256, 0, stream>>>(xb, wt1h, wt1l, av_s1, av_d1, h1b, as1, ad1, N);
        node_agg<128,true><<<cdiv(N, BLK/64), BLK, 0, stream>>>(rowptr, csrsrc, as1, ad1, h1b, b1, agg1, N);

        // ---- layer 2 (h2 in f32; input = relu(agg1), agg1 includes b1) ----
        gemm_mfma<64,true,false><<<cdiv(N, 64), 256, 0, stream>>>(agg1, wt2h, wt2l, av_s2, av_d2, h2, as2, ad2, N);
        node_agg<64,false><<<cdiv(N, BLK/64), BLK, 0, stream>>>(rowptr, csrsrc, as2, ad2, h2, b2, outb, N);
    }
}

// Round 6
// 421.375 us; speedup vs baseline: 11.4820x; 1.0887x over previous
//
#include <hip/hip_runtime.h>

#define NEG_SLOPE 0.2f
static constexpr int BLK = 256;

typedef short bf16x8 __attribute__((ext_vector_type(8)));
typedef float f32x4  __attribute__((ext_vector_type(4)));
typedef unsigned short u16x8 __attribute__((ext_vector_type(8)));

static inline int cdiv(long a, long b){ return (int)((a + b - 1) / b); }

__device__ __forceinline__ unsigned short f2bf(float f){
    unsigned u = __float_as_uint(f);
    u += 0x7fff + ((u >> 16) & 1);          // round-to-nearest-even
    return (unsigned short)(u >> 16);
}
__device__ __forceinline__ float bf2f(unsigned short h){
    return __uint_as_float(((unsigned)h) << 16);
}

// ------------------- W prep: transpose + split into bf16 hi/lo -------------------
__global__ __launch_bounds__(BLK) void prep_w(
    const float* __restrict__ W, int CO,
    unsigned short* __restrict__ Wt_hi, unsigned short* __restrict__ Wt_lo)
{
    int i = blockIdx.x * BLK + threadIdx.x;
    if (i >= CO * 128) return;
    int c = i >> 7, k = i & 127;
    float w = W[k * CO + c];
    unsigned short hi = f2bf(w);
    Wt_hi[i] = hi;
    Wt_lo[i] = f2bf(w - bf2f(hi));
}

// ------------------- MFMA GEMM + attention dots -------------------
template<int CO, bool RELU_IN, bool BF16OUT>
__global__ __launch_bounds__(256) void gemm_mfma(
    const float* __restrict__ X,
    const unsigned short* __restrict__ Wt_hi,
    const unsigned short* __restrict__ Wt_lo,
    const float* __restrict__ avs, const float* __restrict__ avd,
    void* __restrict__ Hout, float* __restrict__ as_out, float* __restrict__ ad_out,
    int N)
{
    constexpr int CT = CO / 16;
    int wave = threadIdx.x >> 6;
    int lane = threadIdx.x & 63;
    int r0 = (blockIdx.x * 4 + wave) * 16;
    if (r0 >= N) return;               // 16 | N
    int rl = lane & 15;
    int g  = lane >> 4;

    const float* xrow = X + (long)(r0 + rl) * 128 + g * 8;

    f32x4 acc[CT];
    #pragma unroll
    for (int t = 0; t < CT; t++) acc[t] = (f32x4)(0.f);

    #pragma unroll
    for (int ks = 0; ks < 4; ks++){
        float4 xa = *(const float4*)(xrow + ks * 32);
        float4 xb = *(const float4*)(xrow + ks * 32 + 4);
        float xv[8] = {xa.x, xa.y, xa.z, xa.w, xb.x, xb.y, xb.z, xb.w};
        bf16x8 ahi, alo;
        #pragma unroll
        for (int j = 0; j < 8; j++){
            float x = xv[j];
            if (RELU_IN) x = fmaxf(x, 0.f);
            unsigned short h = f2bf(x);
            ahi[j] = (short)h;
            alo[j] = (short)f2bf(x - bf2f(h));
        }
        #pragma unroll
        for (int t = 0; t < CT; t++){
            long boff = (long)(t * 16 + rl) * 128 + ks * 32 + g * 8;
            bf16x8 bhi = *(const bf16x8*)(Wt_hi + boff);
            bf16x8 blo = *(const bf16x8*)(Wt_lo + boff);
            acc[t] = __builtin_amdgcn_mfma_f32_16x16x32_bf16(ahi, bhi, acc[t], 0, 0, 0);
            acc[t] = __builtin_amdgcn_mfma_f32_16x16x32_bf16(ahi, blo, acc[t], 0, 0, 0);
            acc[t] = __builtin_amdgcn_mfma_f32_16x16x32_bf16(alo, bhi, acc[t], 0, 0, 0);
        }
    }

    float ps[4] = {0.f, 0.f, 0.f, 0.f}, pd[4] = {0.f, 0.f, 0.f, 0.f};
    #pragma unroll
    for (int t = 0; t < CT; t++){
        float vs = avs[t * 16 + rl], vd = avd[t * 16 + rl];
        #pragma unroll
        for (int r = 0; r < 4; r++){
            float hv = acc[t][r];
            ps[r] += hv * vs;
            pd[r] += hv * vd;
            long idx = (long)(r0 + 4 * g + r) * CO + t * 16 + rl;
            if (BF16OUT) ((unsigned short*)Hout)[idx] = f2bf(hv);
            else         ((float*)Hout)[idx] = hv;
        }
    }
    #pragma unroll
    for (int off = 1; off < 16; off <<= 1){
        #pragma unroll
        for (int r = 0; r < 4; r++){
            ps[r] += __shfl_xor(ps[r], off, 64);
            pd[r] += __shfl_xor(pd[r], off, 64);
        }
    }
    if (rl == 0){
        #pragma unroll
        for (int r = 0; r < 4; r++){
            as_out[r0 + 4 * g + r] = ps[r];
            ad_out[r0 + 4 * g + r] = pd[r];
        }
    }
}

// ------------------- CSR build via per-dst linked lists -------------------
// link: only scattered op is atomicExch; payload store is coalesced by edge id.
__global__ __launch_bounds__(BLK) void link_k(
    const int* __restrict__ src, const int* __restrict__ dst, int E, int Etot,
    int* __restrict__ head, int2* __restrict__ pair)
{
    int e = blockIdx.x * BLK + threadIdx.x;
    if (e >= Etot) return;
    int s, d;
    if (e < E){ s = src[e]; d = dst[e]; } else { s = e - E; d = s; }
    int old = atomicExch(head + d, e);
    pair[e] = make_int2(old, s);        // (next, src) packed, 8B coalesced
}

// degree per node by chain walk (no atomics)
__global__ __launch_bounds__(BLK) void deg_k(
    const int* __restrict__ head, const int2* __restrict__ pair,
    int* __restrict__ counts, int N)
{
    int n = blockIdx.x * BLK + threadIdx.x;
    if (n >= N) return;
    int c = head[n], len = 0;
    while (c >= 0){ len++; c = pair[c].x; }
    counts[n] = len;
}

__global__ __launch_bounds__(256) void scan1_k(
    const int* __restrict__ counts, int N, int* __restrict__ scan1, int* __restrict__ bsum)
{
    __shared__ int sh[256];
    int i = blockIdx.x * 256 + threadIdx.x;
    int v = (i < N) ? counts[i] : 0;
    sh[threadIdx.x] = v;
    __syncthreads();
    #pragma unroll
    for (int off = 1; off < 256; off <<= 1){
        int t = (threadIdx.x >= off) ? sh[threadIdx.x - off] : 0;
        __syncthreads();
        sh[threadIdx.x] += t;
        __syncthreads();
    }
    if (i < N) scan1[i] = sh[threadIdx.x];
    if (threadIdx.x == 255) bsum[blockIdx.x] = sh[255];
}

__global__ __launch_bounds__(256) void scan2_k(int* __restrict__ bsum, int nb)
{
    __shared__ int sh[256];
    int v = (threadIdx.x < nb) ? bsum[threadIdx.x] : 0;
    sh[threadIdx.x] = v;
    __syncthreads();
    #pragma unroll
    for (int off = 1; off < 256; off <<= 1){
        int t = (threadIdx.x >= off) ? sh[threadIdx.x - off] : 0;
        __syncthreads();
        sh[threadIdx.x] += t;
        __syncthreads();
    }
    if (threadIdx.x < nb) bsum[threadIdx.x] = sh[threadIdx.x] - v;  // exclusive
}

__global__ __launch_bounds__(256) void scan3_k(
    const int* __restrict__ counts, const int* __restrict__ scan1,
    const int* __restrict__ bsum, int N, int Etot, int* __restrict__ rowptr)
{
    int i = blockIdx.x * 256 + threadIdx.x;
    if (i < N) rowptr[i] = scan1[i] - counts[i] + bsum[blockIdx.x];
    if (i == 0) rowptr[N] = Etot;
}

// unzip chains into contiguous CSR segments; each segment written by ONE thread
__global__ __launch_bounds__(BLK) void unzip_k(
    const int* __restrict__ head, const int2* __restrict__ pair,
    const int* __restrict__ rowptr, int* __restrict__ csr_src, int N)
{
    int n = blockIdx.x * BLK + threadIdx.x;
    if (n >= N) return;
    int pos = rowptr[n];
    int c = head[n];
    while (c >= 0){
        int2 p = pair[c];
        csr_src[pos++] = p.y;
        c = p.x;
    }
}

// ------------------- fused softmax + aggregation, one wave per dst node ------------
template<int CO, bool BF16H>
__global__ __launch_bounds__(BLK) void node_agg(
    const int* __restrict__ rowptr, const int* __restrict__ csr_src,
    const float* __restrict__ as, const float* __restrict__ ad,
    const void* __restrict__ h, const float* __restrict__ bias,
    float* __restrict__ out, int N)
{
    constexpr int ELEMS = CO / 16;        // elems per lane in quarter-wave mode (8 or 4)
    int node = blockIdx.x * (BLK / 64) + (threadIdx.x >> 6);
    int lane = threadIdx.x & 63;
    if (node >= N) return;
    int start = rowptr[node];
    int deg   = rowptr[node + 1] - start;
    float adv = ad[node];
    int g  = lane >> 4;                   // quarter-group 0..3
    int ql = lane & 15;

    const unsigned short* hb = (const unsigned short*)h;
    const float*          hf = (const float*)h;

    if (deg <= 64){
        int   s = 0;
        float e = -1e30f;
        if (lane < deg){
            s = csr_src[start + lane];
            float v = as[s] + adv;
            e = v > 0.f ? v : NEG_SLOPE * v;
        }
        float m = e;
        #pragma unroll
        for (int off = 32; off; off >>= 1) m = fmaxf(m, __shfl_xor(m, off, 64));
        float ex = (lane < deg) ? __expf(e - m) : 0.f;
        float sum = ex;
        #pragma unroll
        for (int off = 32; off; off >>= 1) sum += __shfl_xor(sum, off, 64);
        float alpha = ex / (sum + 1e-16f);

        float acc[ELEMS];
        #pragma unroll
        for (int i = 0; i < ELEMS; i++) acc[i] = 0.f;

        int j = 0;
        for (; j + 7 < deg; j += 8){
            int e0 = j + g, e1 = j + 4 + g;
            int   s0 = __shfl(s, e0, 64),      s1 = __shfl(s, e1, 64);
            float a0 = __shfl(alpha, e0, 64),  a1 = __shfl(alpha, e1, 64);
            if (BF16H){
                u16x8 h0 = *(const u16x8*)(hb + (long)s0 * CO + ql * ELEMS);
                u16x8 h1 = *(const u16x8*)(hb + (long)s1 * CO + ql * ELEMS);
                #pragma unroll
                for (int i = 0; i < ELEMS; i++)
                    acc[i] += a0 * bf2f(h0[i]) + a1 * bf2f(h1[i]);
            } else {
                float4 h0 = *(const float4*)(hf + (long)s0 * CO + ql * ELEMS);
                float4 h1 = *(const float4*)(hf + (long)s1 * CO + ql * ELEMS);
                acc[0]       += a0 * h0.x + a1 * h1.x;
                acc[1]       += a0 * h0.y + a1 * h1.y;
                acc[2]       += a0 * h0.z + a1 * h1.z;
                acc[ELEMS-1] += a0 * h0.w + a1 * h1.w;
            }
        }
        for (; j + 3 < deg; j += 4){
            int e0 = j + g;
            int   s0 = __shfl(s, e0, 64);
            float a0 = __shfl(alpha, e0, 64);
            if (BF16H){
                u16x8 h0 = *(const u16x8*)(hb + (long)s0 * CO + ql * ELEMS);
                #pragma unroll
                for (int i = 0; i < ELEMS; i++) acc[i] += a0 * bf2f(h0[i]);
            } else {
                float4 h0 = *(const float4*)(hf + (long)s0 * CO + ql * ELEMS);
                acc[0] += a0 * h0.x; acc[1] += a0 * h0.y;
                acc[2] += a0 * h0.z; acc[ELEMS-1] += a0 * h0.w;
            }
        }
        if (j < deg){
            int rem = deg - j;
            int e0 = min(j + g, deg - 1);
            int   s0 = __shfl(s, e0, 64);
            float a0 = __shfl(alpha, e0, 64);
            if (g < rem){
                if (BF16H){
                    u16x8 h0 = *(const u16x8*)(hb + (long)s0 * CO + ql * ELEMS);
                    #pragma unroll
                    for (int i = 0; i < ELEMS; i++) acc[i] += a0 * bf2f(h0[i]);
                } else {
                    float4 h0 = *(const float4*)(hf + (long)s0 * CO + ql * ELEMS);
                    acc[0] += a0 * h0.x; acc[1] += a0 * h0.y;
                    acc[2] += a0 * h0.z; acc[ELEMS-1] += a0 * h0.w;
                }
            }
        }
        #pragma unroll
        for (int i = 0; i < ELEMS; i++){
            acc[i] += __shfl_xor(acc[i], 16, 64);
            acc[i] += __shfl_xor(acc[i], 32, 64);
        }
        if (g == 0){
            float* o = out + (long)node * CO + ql * ELEMS;
            #pragma unroll
            for (int i = 0; i < ELEMS; i += 4){
                float4 ov;
                ov.x = acc[i+0] + bias[ql * ELEMS + i + 0];
                ov.y = acc[i+1] + bias[ql * ELEMS + i + 1];
                ov.z = acc[i+2] + bias[ql * ELEMS + i + 2];
                ov.w = acc[i+3] + bias[ql * ELEMS + i + 3];
                *(float4*)(o + i) = ov;
            }
        }
    } else {
        constexpr int VPL = CO / 64;
        float accf[VPL];
        #pragma unroll
        for (int i = 0; i < VPL; i++) accf[i] = 0.f;
        float m = -1e30f;
        for (int jj = lane; jj < deg; jj += 64){
            int sj = csr_src[start + jj];
            float v = as[sj] + adv; v = v > 0.f ? v : NEG_SLOPE * v;
            m = fmaxf(m, v);
        }
        #pragma unroll
        for (int off = 32; off; off >>= 1) m = fmaxf(m, __shfl_xor(m, off, 64));
        float sum = 0.f;
        for (int jj = lane; jj < deg; jj += 64){
            int sj = csr_src[start + jj];
            float v = as[sj] + adv; v = v > 0.f ? v : NEG_SLOPE * v;
            sum += __expf(v - m);
        }
        #pragma unroll
        for (int off = 32; off; off >>= 1) sum += __shfl_xor(sum, off, 64);
        float inv = 1.f / (sum + 1e-16f);
        for (int jj = 0; jj < deg; jj++){
            int sj = csr_src[start + jj];
            float v = as[sj] + adv; v = v > 0.f ? v : NEG_SLOPE * v;
            float aj = __expf(v - m) * inv;
            if (BF16H){
                const unsigned short* hr = hb + (long)sj * CO + lane * VPL;
                #pragma unroll
                for (int i = 0; i < VPL; i++) accf[i] += aj * bf2f(hr[i]);
            } else {
                const float* hr = hf + (long)sj * CO + lane * VPL;
                #pragma unroll
                for (int i = 0; i < VPL; i++) accf[i] += aj * hr[i];
            }
        }
        float* o = out + (long)node * CO + lane * VPL;
        #pragma unroll
        for (int i = 0; i < VPL; i++) o[i] = accf[i] + bias[lane * VPL + i];
    }
}

extern "C" void kernel_launch(void* const* d_in, const int* in_sizes, int n_in,
                              void* d_out, int out_size, void* d_ws, size_t ws_size,
                              hipStream_t stream)
{
    const float* fea  = (const float*)d_in[0];  // [B,N,128]
    const int*   ei   = (const int*)  d_in[1];  // [B,2,E]
    const float* W1   = (const float*)d_in[2];  // [128,128]
    const float* av_s1= (const float*)d_in[3];
    const float* av_d1= (const float*)d_in[4];
    const float* b1   = (const float*)d_in[5];
    const float* W2   = (const float*)d_in[6];  // [128,64]
    const float* av_s2= (const float*)d_in[7];
    const float* av_d2= (const float*)d_in[8];
    const float* b2   = (const float*)d_in[9];
    float* out = (float*)d_out;

    const int B = 2;
    const int N = out_size / (B * 64);          // 50000
    const int E = in_sizes[1] / (2 * B);        // 800000
    const int Etot = E + N;

    // workspace layout (float units; all chunk sizes even -> 8B alignment holds)
    float* ws = (float*)d_ws;
    size_t off = 0;
    unsigned short* h1b = (unsigned short*)(ws + off); off += (size_t)N * 64;  // bf16 [N][128]
    float* agg1 = ws + off; off += (size_t)N * 128;
    float* h2   = ws + off; off += (size_t)N * 64;
    float* as1  = ws + off; off += N;
    float* ad1  = ws + off; off += N;
    float* as2  = ws + off; off += N;
    float* ad2  = ws + off; off += N;
    int* counts = (int*)(ws + off); off += N;
    int* head   = (int*)(ws + off); off += N;
    int* scan1b = (int*)(ws + off); off += N;
    int* bsum   = (int*)(ws + off); off += 256;
    int* rowptr = (int*)(ws + off); off += (N + 2);  // padded to even
    int* csrsrc = (int*)(ws + off); off += Etot;
    off += (off & 1);                                // 8B align for pair
    int2* pair  = (int2*)(ws + off); off += (size_t)2 * Etot;
    unsigned short* wt1h = (unsigned short*)(ws + off); off += 128*128/2;
    unsigned short* wt1l = (unsigned short*)(ws + off); off += 128*128/2;
    unsigned short* wt2h = (unsigned short*)(ws + off); off += 64*128/2;
    unsigned short* wt2l = (unsigned short*)(ws + off); off += 64*128/2;

    const int nb = cdiv(N, 256);

    prep_w<<<cdiv(128*128, BLK), BLK, 0, stream>>>(W1, 128, wt1h, wt1l);
    prep_w<<<cdiv(64*128,  BLK), BLK, 0, stream>>>(W2, 64,  wt2h, wt2l);

    for (int b = 0; b < B; b++){
        const int* srcp = ei + (size_t)b * 2 * E;
        const int* dstp = srcp + E;
        const float* xb = fea + (size_t)b * N * 128;
        float* outb = out + (size_t)b * N * 64;

        // ---- CSR build via linked lists (shared by both layers) ----
        hipMemsetAsync(head, 0xFF, (size_t)N * sizeof(int), stream);   // head = -1
        link_k<<<cdiv(Etot, BLK), BLK, 0, stream>>>(srcp, dstp, E, Etot, head, pair);
        deg_k<<<cdiv(N, BLK), BLK, 0, stream>>>(head, pair, counts, N);
        scan1_k<<<nb, 256, 0, stream>>>(counts, N, scan1b, bsum);
        scan2_k<<<1, 256, 0, stream>>>(bsum, nb);
        scan3_k<<<nb, 256, 0, stream>>>(counts, scan1b, bsum, N, Etot, rowptr);
        unzip_k<<<cdiv(N, BLK), BLK, 0, stream>>>(head, pair, rowptr, csrsrc, N);

        // ---- layer 1 (h1 in bf16) ----
        gemm_mfma<128,false,true><<<cdiv(N, 64), 256, 0, stream>>>(xb, wt1h, wt1l, av_s1, av_d1, h1b, as1, ad1, N);
        node_agg<128,true><<<cdiv(N, BLK/64), BLK, 0, stream>>>(rowptr, csrsrc, as1, ad1, h1b, b1, agg1, N);

        // ---- layer 2 (h2 in f32; input = relu(agg1), agg1 includes b1) ----
        gemm_mfma<64,true,false><<<cdiv(N, 64), 256, 0, stream>>>(agg1, wt2h, wt2l, av_s2, av_d2, h2, as2, ad2, N);
        node_agg<64,false><<<cdiv(N, BLK/64), BLK, 0, stream>>>(rowptr, csrsrc, as2, ad2, h2, b2, outb, N);
    }
}